// Round 15
// baseline (1000.032 us; speedup 1.0000x reference)
//
#include <hip/hip_runtime.h>
#include <hip/hip_bf16.h>

typedef unsigned short ushort_t;
typedef __attribute__((ext_vector_type(8))) short bf16x8;
typedef __attribute__((ext_vector_type(4))) float f32x4;

constexpr int CB = 2, CS = 512, CD = 1024, CH = 16, CHD = 64;
constexpr int CST = 2048, CLT = 6144;
constexpr int CKST = 204, CKLT = 614;

__device__ __forceinline__ float u2f(unsigned u) { return __uint_as_float(u); }
__device__ __forceinline__ float bf2f(ushort_t u) {
  return __uint_as_float(((unsigned)u) << 16);
}
__device__ __forceinline__ ushort_t f2bf(float f) {
  __hip_bfloat16 h = __float2bfloat16(f);
  return *reinterpret_cast<ushort_t*>(&h);
}
// monotone 16-bit key: mono(a) > mono(b) <=> bf16 a > b
__device__ __forceinline__ unsigned mono16(ushort_t u) {
  return (u & 0x8000) ? (unsigned)((ushort_t)~u) : (unsigned)(u | 0x8000);
}

__device__ __forceinline__ float block_sum_f(float v, float* scratch, int tid) {
#pragma unroll
  for (int o = 32; o > 0; o >>= 1) v += __shfl_down(v, o, 64);
  if ((tid & 63) == 0) scratch[tid >> 6] = v;
  __syncthreads();
  float r = (scratch[0] + scratch[1]) + (scratch[2] + scratch[3]);
  __syncthreads();
  return r;
}

// ---------------- K0: bank-mix coefficients ----------------
__global__ __launch_bounds__(256) void prep_kernel(
    const float* __restrict__ st_imp, const float* __restrict__ lt_imp,
    float* __restrict__ scal) {
  __shared__ float scr[4];
  int tid = threadIdx.x;
  float s = 0.f, l = 0.f;
  for (int i = tid; i < CST; i += 256) s += st_imp[i];
  for (int i = tid; i < CLT; i += 256) l += lt_imp[i];
  float ssum = block_sum_f(s, scr, tid);
  float lsum = block_sum_f(l, scr, tid);
  if (tid == 0) {
    float sw = 1.f / (1.f + __expf(-(ssum / CST)));
    float lw = 1.f / (1.f + __expf(-(lsum / CLT)));
    float tot = sw + lw;
    scal[0] = sw / tot;
    scal[1] = lw / tot;
  }
}

// ---------------- K1: MFMA qproj: Q = X @ Wq + bq (fp32 out) ------------------
__global__ __launch_bounds__(256) void qproj_mfma(
    const float* __restrict__ X, const float* __restrict__ Wq,
    const float* __restrict__ bq, float* __restrict__ Qout) {
  __shared__ ushort_t As[64][40];   // X tile  [row][k]
  __shared__ ushort_t BsT[64][40];  // Wq tile [col][k] (transposed)
  int tid = threadIdx.x;
  int l = tid & 63;
  int w = tid >> 6;
  int bm = (blockIdx.x >> 4) * 64;
  int bn = (blockIdx.x & 15) * 64;

  int arow = l & 15;
  int koff = (l >> 4) * 8;

  f32x4 acc[4];
#pragma unroll
  for (int c = 0; c < 4; ++c) acc[c] = {0.f, 0.f, 0.f, 0.f};

  for (int k0 = 0; k0 < CD; k0 += 32) {
#pragma unroll
    for (int e = 0; e < 2; ++e) {
      int idx = tid + e * 256;
      int r = idx >> 3;
      int kk4 = (idx & 7) * 4;
      float4 v = *(const float4*)&X[(size_t)(bm + r) * CD + k0 + kk4];
      uint2 p;
      p.x = (unsigned)f2bf(v.x) | ((unsigned)f2bf(v.y) << 16);
      p.y = (unsigned)f2bf(v.z) | ((unsigned)f2bf(v.w) << 16);
      *(uint2*)&As[r][kk4] = p;
    }
#pragma unroll
    for (int e = 0; e < 2; ++e) {
      int idx = tid + e * 256;
      int kk = idx >> 4;
      int nn4 = (idx & 15) * 4;
      float4 v = *(const float4*)&Wq[(size_t)(k0 + kk) * CD + bn + nn4];
      BsT[nn4 + 0][kk] = f2bf(v.x);
      BsT[nn4 + 1][kk] = f2bf(v.y);
      BsT[nn4 + 2][kk] = f2bf(v.z);
      BsT[nn4 + 3][kk] = f2bf(v.w);
    }
    __syncthreads();

    bf16x8 af = *(const bf16x8*)&As[w * 16 + arow][koff];
#pragma unroll
    for (int c = 0; c < 4; ++c) {
      bf16x8 bfv = *(const bf16x8*)&BsT[c * 16 + arow][koff];
      acc[c] = __builtin_amdgcn_mfma_f32_16x16x32_bf16(af, bfv, acc[c], 0, 0, 0);
    }
    __syncthreads();
  }

  int col = l & 15;
  int row4 = (l >> 4) * 4;
#pragma unroll
  for (int c = 0; c < 4; ++c) {
    float bb = bq[bn + c * 16 + col];
#pragma unroll
    for (int r = 0; r < 4; ++r)
      Qout[(size_t)(bm + w * 16 + row4 + r) * CD + bn + c * 16 + col] =
          acc[c][r] + bb;
  }
}

// ---------------- K-repack: K[m][h*64+d] f32 -> KH[h][m][64] bf16 -------------
template <int M>
__global__ __launch_bounds__(256) void krepack_kernel(
    const float* __restrict__ K, ushort_t* __restrict__ KH) {
  int m = blockIdx.x * 4 + (threadIdx.x >> 6);
  int d = threadIdx.x & 63;
  const float* src = K + (size_t)m * CD;
#pragma unroll
  for (int h = 0; h < CH; ++h) {
    KH[((size_t)h * M + m) * 64 + d] = f2bf(src[h * CHD + d]);
  }
}

// ---------------- K2 v12: v11 + pipelined phase1 + pair-split select ---------
// 16 waves, 8 queries/block. Phase 1: software-pipelined 16-key MFMA tiles
// (prefetch tile t+1 K-fragments before tile t MFMA). Select: ALL 16 waves run
// the register binary search for query (w&7) redundantly (waves 8-15 were
// idle); wave pair (q,q+8) then SPLITS compaction and w-fill halves into
// disjoint il32 ranges. PV: pair-split, il32 single-read (m | bf16w<<16).
template <int M, int LCAP>
__global__ __launch_bounds__(1024, 1) void attn_v12(
    const float* __restrict__ Q, const ushort_t* __restrict__ KH,
    const float* __restrict__ Vp, const float* __restrict__ imp,
    const float* __restrict__ scal, int scal_idx, int kth,
    float* __restrict__ mem_out, int add_to) {
  constexpr int MP = M + 16;     // padded row (u16)
  constexpr int NGRP = M / 256;  // uint2 per lane covering full M
  constexpr int HG = NGRP / 2;   // groups per half-wave (24->12 lt, 8->4 st)
  constexpr int NT = M / 256;    // 16-key tiles per wave strip

  __shared__ ushort_t sc_l[8][MP];
  __shared__ unsigned il32[8][LCAP];
  __shared__ float q_l[8][CHD];
  __shared__ float wmax[16][8];
  __shared__ float wsp2[8][2];
  __shared__ int nsel[8];
  __shared__ float4 pacc[8][2][16];

  int tid = threadIdx.x;
  int l = tid & 63;
  int w = tid >> 6;  // 0..15
  int idx = blockIdx.x;
  int sg = idx & (CS / 8 - 1);
  int h = (idx >> 6) & (CH - 1);
  int b = idx >> 10;
  int s0 = sg * 8;
  int h6 = h * CHD;

  if (tid < 512)
    q_l[tid >> 6][tid & 63] = Q[((size_t)(b * CS + s0 + (tid >> 6))) * CD + h6 + (tid & 63)];
  __syncthreads();

  // ---- B-fragments: col = lane&15 (8 real query slots), k = (lane>>4)*8 + j
  int col = l & 15;
  int kbase = (l >> 4) * 8;
  bf16x8 bq0, bq1;
#pragma unroll
  for (int j = 0; j < 8; ++j) { bq0[j] = 0; bq1[j] = 0; }
  if (col < 8) {
#pragma unroll
    for (int j = 0; j < 8; ++j) {
      bq0[j] = (short)f2bf(q_l[col][kbase + j]);
      bq1[j] = (short)f2bf(q_l[col][32 + kbase + j]);
    }
  }

  // ---- phase 1: software-pipelined MFMA scores over strip ----
  float lmax_q = -1e30f;
  {
    const ushort_t* kp = KH + (size_t)h * M * 64 +
                         (size_t)(w * (M / 16) + col) * 64 + kbase;
    bf16x8 a0 = *(const bf16x8*)kp;
    bf16x8 a1 = *(const bf16x8*)(kp + 32);
#pragma unroll 1
    for (int tile = 0; tile < NT; ++tile) {
      // prefetch next tile before consuming current
      const ushort_t* np = kp + ((tile + 1 < NT) ? (tile + 1) * 1024 : 0);
      bf16x8 n0 = *(const bf16x8*)np;
      bf16x8 n1 = *(const bf16x8*)(np + 32);
      f32x4 dfrag = {0.f, 0.f, 0.f, 0.f};
      dfrag = __builtin_amdgcn_mfma_f32_16x16x32_bf16(a0, bq0, dfrag, 0, 0, 0);
      dfrag = __builtin_amdgcn_mfma_f32_16x16x32_bf16(a1, bq1, dfrag, 0, 0, 0);
      if (col < 8) {
        int mb = w * (M / 16) + tile * 16 + (l >> 4) * 4;
        float4 ip = *(const float4*)&imp[mb];
        float s0v = dfrag[0] * 0.125f * ip.x;
        float s1v = dfrag[1] * 0.125f * ip.y;
        float s2v = dfrag[2] * 0.125f * ip.z;
        float s3v = dfrag[3] * 0.125f * ip.w;
        lmax_q = fmaxf(lmax_q, fmaxf(fmaxf(s0v, s1v), fmaxf(s2v, s3v)));
        unsigned p0 = (unsigned)f2bf(s0v) | ((unsigned)f2bf(s1v) << 16);
        unsigned p1 = (unsigned)f2bf(s2v) | ((unsigned)f2bf(s3v) << 16);
        *(uint2*)&sc_l[col][mb] = make_uint2(p0, p1);
      }
      a0 = n0;
      a1 = n1;
    }
  }
  lmax_q = fmaxf(lmax_q, __shfl_xor(lmax_q, 16, 64));
  lmax_q = fmaxf(lmax_q, __shfl_xor(lmax_q, 32, 64));
  if (l < 8) wmax[w][l] = lmax_q;
  __syncthreads();

  // ---- select: ALL waves; wave pair (wq, wq+8) redundant search, split tails
  int wq = w & 7;
  int shalf = w >> 3;
  float t = wmax[0][wq];
#pragma unroll
  for (int ww = 1; ww < 16; ++ww) t = fmaxf(t, wmax[ww][wq]);

  unsigned mreg[2 * NGRP];
#pragma unroll
  for (int g = 0; g < NGRP; ++g) {
    uint2 sv = *(const uint2*)&sc_l[wq][g * 256 + 4 * l];
    mreg[2 * g] = mono16((ushort_t)(sv.x & 0xFFFF)) |
                  (mono16((ushort_t)(sv.x >> 16)) << 16);
    mreg[2 * g + 1] = mono16((ushort_t)(sv.y & 0xFFFF)) |
                      (mono16((ushort_t)(sv.y >> 16)) << 16);
  }

  unsigned lo = 0u, hi = 0xFFFFu;
#pragma unroll 1
  for (int it = 0; it < 16; ++it) {
    unsigned mid = lo + ((hi - lo + 1u) >> 1);
    int cnt = 0;
#pragma unroll
    for (int j = 0; j < 2 * NGRP; ++j) {
      cnt += (int)((mreg[j] & 0xFFFFu) >= mid);
      cnt += (int)((mreg[j] >> 16) >= mid);
    }
#pragma unroll
    for (int off = 1; off < 64; off <<= 1) cnt += __shfl_xor(cnt, off, 64);
    if (cnt >= kth) lo = mid;
    else hi = mid - 1u;
  }
  unsigned thr = lo;

  // base position for this half = count of selected in groups [0, HG)
  int base = 0;
  if (shalf) {
    int c = 0;
#pragma unroll
    for (int j = 0; j < 2 * HG; ++j) {
      c += (int)(((mreg[j] & 0xFFFFu)) >= thr);
      c += (int)(((mreg[j] >> 16)) >= thr);
    }
#pragma unroll
    for (int off = 1; off < 64; off <<= 1) c += __shfl_xor(c, off, 64);
    base = c;
  }

  // ballot compaction of own half's groups into il32 (disjoint ranges)
  unsigned long long lt_mask = (1ull << l) - 1ull;
  int pos = base;
#pragma unroll
  for (int g = shalf * HG; g < (shalf + 1) * HG; ++g) {
#pragma unroll
    for (int e = 0; e < 4; ++e) {
      unsigned mv = (mreg[2 * g + (e >> 1)] >> ((e & 1) * 16)) & 0xFFFFu;
      bool sel = mv >= thr;
      unsigned long long mask = __ballot(sel);
      if (sel) {
        int p = pos + __builtin_popcountll(mask & lt_mask);
        if (p < LCAP) il32[wq][p] = (unsigned)(g * 256 + 4 * l + e);
      }
      pos += __builtin_popcountll(mask);
    }
  }
  if (shalf == 1 && l == 0) nsel[wq] = pos < LCAP ? pos : LCAP;
  __syncthreads();

  // ---- w-fill split: exp once per selected row; pack weight into high16 ----
  {
    int n = nsel[wq];
    int f0 = shalf ? (n >> 1) : 0;
    int f1 = shalf ? n : (n >> 1);
    float wsum = 0.f;
    for (int i = f0 + l; i < f1; i += 64) {
      unsigned m = il32[wq][i];
      float wv = __expf(bf2f(sc_l[wq][m]) - t);
      wsum += wv;
      il32[wq][i] = m | ((unsigned)f2bf(wv) << 16);
    }
#pragma unroll
    for (int off = 1; off < 64; off <<= 1) wsum += __shfl_xor(wsum, off, 64);
    if (l == 0) wsp2[wq][shalf] = wsum;
  }
  __syncthreads();

  // ---- PV: wave pair (wq, shalf) splits the selected list ----
  {
    int n = nsel[wq];
    int n0 = (n >> 1) & ~7;
    int i0 = shalf ? n0 : 0;
    int i1 = shalf ? n : n0;
    int g = l >> 4;
    int dl = l & 15;
    const float* Vb = Vp + h6 + 4 * dl;
    f32x4 acc = {0.f, 0.f, 0.f, 0.f};
    int i = i0;
    for (; i + 8 <= i1; i += 8) {
      unsigned eA = il32[wq][i + g];
      unsigned eB = il32[wq][i + 4 + g];
      unsigned mA = eA & 0xFFFFu, mB = eB & 0xFFFFu;
      float wA = bf2f((ushort_t)(eA >> 16));
      float wB = bf2f((ushort_t)(eB >> 16));
      float4 vA = *(const float4*)(Vb + ((size_t)mA << 10));
      float4 vB = *(const float4*)(Vb + ((size_t)mB << 10));
      acc[0] += wA * vA.x + wB * vB.x;
      acc[1] += wA * vA.y + wB * vB.y;
      acc[2] += wA * vA.z + wB * vB.z;
      acc[3] += wA * vA.w + wB * vB.w;
    }
    for (; i + 4 <= i1; i += 4) {
      unsigned e = il32[wq][i + g];
      unsigned m = e & 0xFFFFu;
      float wv = bf2f((ushort_t)(e >> 16));
      float4 v = *(const float4*)(Vb + ((size_t)m << 10));
      acc[0] += wv * v.x;
      acc[1] += wv * v.y;
      acc[2] += wv * v.z;
      acc[3] += wv * v.w;
    }
    for (; i < i1; ++i) {
      if (g == 0) {
        unsigned e = il32[wq][i];
        unsigned m = e & 0xFFFFu;
        float wv = bf2f((ushort_t)(e >> 16));
        float4 v = *(const float4*)(Vb + ((size_t)m << 10));
        acc[0] += wv * v.x;
        acc[1] += wv * v.y;
        acc[2] += wv * v.z;
        acc[3] += wv * v.w;
      }
    }
#pragma unroll
    for (int c = 0; c < 4; ++c) {
      acc[c] += __shfl_xor(acc[c], 16, 64);
      acc[c] += __shfl_xor(acc[c], 32, 64);
    }
    if (l < 16) {
      float4 o;
      o.x = acc[0]; o.y = acc[1]; o.z = acc[2]; o.w = acc[3];
      pacc[wq][shalf][dl] = o;
    }
  }
  __syncthreads();

  if (w < 8 && l < 16) {
    int dl = l;
    float4 p0 = pacc[w][0][dl];
    float4 p1 = pacc[w][1][dl];
    float wsc = scal[scal_idx] / (wsp2[w][0] + wsp2[w][1]);
    size_t off = ((size_t)(b * CS + s0 + w)) * CD + h6 + 4 * dl;
    float4 o;
    o.x = (p0.x + p1.x) * wsc;
    o.y = (p0.y + p1.y) * wsc;
    o.z = (p0.z + p1.z) * wsc;
    o.w = (p0.w + p1.w) * wsc;
    if (add_to) {
      float4 prev = *(const float4*)&mem_out[off];
      o.x += prev.x; o.y += prev.y; o.z += prev.z; o.w += prev.w;
    }
    *(float4*)&mem_out[off] = o;
  }
}

// ---------------- K3: gate + residual + LayerNorm ----------------
__global__ __launch_bounds__(256) void gate_ln_kernel(
    const float* __restrict__ X, const float* __restrict__ Mem,
    const float* __restrict__ Wg, const float* __restrict__ bg,
    const float* __restrict__ lng, const float* __restrict__ lnb,
    float* __restrict__ Out) {
  __shared__ float scr[4];
  int tid = threadIdx.x;
  int row = blockIdx.x;
  int d0 = tid * 4;

  float4 px = *(const float4*)(X + (size_t)row * CD + d0);
  float4 pm = *(const float4*)(Mem + (size_t)row * CD + d0);
  float4 wi = *(const float4*)(Wg + d0);
  float4 wm = *(const float4*)(Wg + CD + d0);

  float t = px.x * wi.x + px.y * wi.y + px.z * wi.z + px.w * wi.w +
            pm.x * wm.x + pm.y * wm.y + pm.z * wm.z + pm.w * wm.w;
  float z = block_sum_f(t, scr, tid) + bg[0];
  float gate = 1.f / (1.f + __expf(-z));

  float xr0 = px.x + pm.x * gate;
  float xr1 = px.y + pm.y * gate;
  float xr2 = px.z + pm.z * gate;
  float xr3 = px.w + pm.w * gate;

  float ssum = block_sum_f(xr0 + xr1 + xr2 + xr3, scr, tid);
  float ssq = block_sum_f(xr0 * xr0 + xr1 * xr1 + xr2 * xr2 + xr3 * xr3, scr, tid);
  float mu = ssum * (1.f / CD);
  float var = ssq * (1.f / CD) - mu * mu;
  float inv = rsqrtf(var + 1e-5f);

  float4 pg = *(const float4*)(lng + d0);
  float4 pb = *(const float4*)(lnb + d0);
  float4 o;
  o.x = (xr0 - mu) * inv * pg.x + pb.x;
  o.y = (xr1 - mu) * inv * pg.y + pb.y;
  o.z = (xr2 - mu) * inv * pg.z + pb.z;
  o.w = (xr3 - mu) * inv * pg.w + pb.w;
  *(float4*)(Out + (size_t)row * CD + d0) = o;
}

extern "C" void kernel_launch(void* const* d_in, const int* in_sizes, int n_in,
                              void* d_out, int out_size, void* d_ws, size_t ws_size,
                              hipStream_t stream) {
  const float* inputs = (const float*)d_in[0];
  const float* Wq = (const float*)d_in[1];
  const float* bq = (const float*)d_in[2];
  const float* st_keys = (const float*)d_in[3];
  const float* st_values = (const float*)d_in[4];
  const float* lt_keys = (const float*)d_in[5];
  const float* lt_values = (const float*)d_in[6];
  const float* st_imp = (const float*)d_in[7];
  const float* lt_imp = (const float*)d_in[8];
  const float* Wg = (const float*)d_in[9];
  const float* bg = (const float*)d_in[10];
  const float* ln_g = (const float*)d_in[11];
  const float* ln_b = (const float*)d_in[12];
  float* out = (float*)d_out;

  size_t nQ = (size_t)CB * CS * CD;
  float* Qws = (float*)d_ws;
  float* Memws = Qws + nQ;
  float* scal = Memws + nQ;
  ushort_t* KHst = (ushort_t*)(scal + 64);
  ushort_t* KHlt = KHst + (size_t)CD * CST;

  int nblk8 = CB * CH * (CS / 8);  // 2048

  prep_kernel<<<1, 256, 0, stream>>>(st_imp, lt_imp, scal);
  qproj_mfma<<<256, 256, 0, stream>>>(inputs, Wq, bq, Qws);
  krepack_kernel<CST><<<CST / 4, 256, 0, stream>>>(st_keys, KHst);
  krepack_kernel<CLT><<<CLT / 4, 256, 0, stream>>>(lt_keys, KHlt);
  attn_v12<CST, 320><<<nblk8, 1024, 0, stream>>>(
      Qws, KHst, st_values, st_imp, scal, 0, CKST, Memws, 0);
  attn_v12<CLT, 896><<<nblk8, 1024, 0, stream>>>(
      Qws, KHlt, lt_values, lt_imp, scal, 1, CKLT, Memws, 1);
  gate_ln_kernel<<<CB * CS, 256, 0, stream>>>(inputs, Memws, Wg, bg, ln_g, ln_b, out);
}

// Round 16
// 792.245 us; speedup vs baseline: 1.2623x; 1.2623x over previous
//
#include <hip/hip_runtime.h>
#include <hip/hip_bf16.h>

typedef unsigned short ushort_t;
typedef __attribute__((ext_vector_type(8))) short bf16x8;
typedef __attribute__((ext_vector_type(4))) float f32x4;

constexpr int CB = 2, CS = 512, CD = 1024, CH = 16, CHD = 64;
constexpr int CST = 2048, CLT = 6144;
constexpr int CKST = 204, CKLT = 614;

__device__ __forceinline__ float u2f(unsigned u) { return __uint_as_float(u); }
__device__ __forceinline__ float bf2f(ushort_t u) {
  return __uint_as_float(((unsigned)u) << 16);
}
__device__ __forceinline__ ushort_t f2bf(float f) {
  __hip_bfloat16 h = __float2bfloat16(f);
  return *reinterpret_cast<ushort_t*>(&h);
}
// monotone 16-bit key: mono(a) > mono(b) <=> bf16 a > b
__device__ __forceinline__ unsigned mono16(ushort_t u) {
  return (u & 0x8000) ? (unsigned)((ushort_t)~u) : (unsigned)(u | 0x8000);
}

__device__ __forceinline__ float block_sum_f(float v, float* scratch, int tid) {
#pragma unroll
  for (int o = 32; o > 0; o >>= 1) v += __shfl_down(v, o, 64);
  if ((tid & 63) == 0) scratch[tid >> 6] = v;
  __syncthreads();
  float r = (scratch[0] + scratch[1]) + (scratch[2] + scratch[3]);
  __syncthreads();
  return r;
}

// ---------------- K0: bank-mix coefficients ----------------
__global__ __launch_bounds__(256) void prep_kernel(
    const float* __restrict__ st_imp, const float* __restrict__ lt_imp,
    float* __restrict__ scal) {
  __shared__ float scr[4];
  int tid = threadIdx.x;
  float s = 0.f, l = 0.f;
  for (int i = tid; i < CST; i += 256) s += st_imp[i];
  for (int i = tid; i < CLT; i += 256) l += lt_imp[i];
  float ssum = block_sum_f(s, scr, tid);
  float lsum = block_sum_f(l, scr, tid);
  if (tid == 0) {
    float sw = 1.f / (1.f + __expf(-(ssum / CST)));
    float lw = 1.f / (1.f + __expf(-(lsum / CLT)));
    float tot = sw + lw;
    scal[0] = sw / tot;
    scal[1] = lw / tot;
  }
}

// ---------------- K1: MFMA qproj: Q = X @ Wq + bq (fp32 out) ------------------
// 64x64 tile per block (256 thr, 4 waves; wave w = 16 rows). K-step 32.
// LDS staged bf16 with stride 40 (80B) to spread banks.
__global__ __launch_bounds__(256) void qproj_mfma(
    const float* __restrict__ X, const float* __restrict__ Wq,
    const float* __restrict__ bq, float* __restrict__ Qout) {
  __shared__ ushort_t As[64][40];   // X tile  [row][k]
  __shared__ ushort_t BsT[64][40];  // Wq tile [col][k] (transposed)
  int tid = threadIdx.x;
  int l = tid & 63;
  int w = tid >> 6;
  int bm = (blockIdx.x >> 4) * 64;
  int bn = (blockIdx.x & 15) * 64;

  int arow = l & 15;
  int koff = (l >> 4) * 8;

  f32x4 acc[4];
#pragma unroll
  for (int c = 0; c < 4; ++c) acc[c] = {0.f, 0.f, 0.f, 0.f};

  for (int k0 = 0; k0 < CD; k0 += 32) {
    // stage As: 64x32 fp32 -> bf16
#pragma unroll
    for (int e = 0; e < 2; ++e) {
      int idx = tid + e * 256;
      int r = idx >> 3;
      int kk4 = (idx & 7) * 4;
      float4 v = *(const float4*)&X[(size_t)(bm + r) * CD + k0 + kk4];
      uint2 p;
      p.x = (unsigned)f2bf(v.x) | ((unsigned)f2bf(v.y) << 16);
      p.y = (unsigned)f2bf(v.z) | ((unsigned)f2bf(v.w) << 16);
      *(uint2*)&As[r][kk4] = p;
    }
    // stage BsT: Wq[k0+kk][bn+nn] -> BsT[nn][kk]
#pragma unroll
    for (int e = 0; e < 2; ++e) {
      int idx = tid + e * 256;
      int kk = idx >> 4;
      int nn4 = (idx & 15) * 4;
      float4 v = *(const float4*)&Wq[(size_t)(k0 + kk) * CD + bn + nn4];
      BsT[nn4 + 0][kk] = f2bf(v.x);
      BsT[nn4 + 1][kk] = f2bf(v.y);
      BsT[nn4 + 2][kk] = f2bf(v.z);
      BsT[nn4 + 3][kk] = f2bf(v.w);
    }
    __syncthreads();

    bf16x8 af = *(const bf16x8*)&As[w * 16 + arow][koff];
#pragma unroll
    for (int c = 0; c < 4; ++c) {
      bf16x8 bfv = *(const bf16x8*)&BsT[c * 16 + arow][koff];
      acc[c] = __builtin_amdgcn_mfma_f32_16x16x32_bf16(af, bfv, acc[c], 0, 0, 0);
    }
    __syncthreads();
  }

  // epilogue: D col = lane&15, row = (lane>>4)*4 + reg
  int col = l & 15;
  int row4 = (l >> 4) * 4;
#pragma unroll
  for (int c = 0; c < 4; ++c) {
    float bb = bq[bn + c * 16 + col];
#pragma unroll
    for (int r = 0; r < 4; ++r)
      Qout[(size_t)(bm + w * 16 + row4 + r) * CD + bn + c * 16 + col] =
          acc[c][r] + bb;
  }
}

// ---------------- K-repack: K[m][h*64+d] f32 -> KH[h][m][64] bf16 -------------
template <int M>
__global__ __launch_bounds__(256) void krepack_kernel(
    const float* __restrict__ K, ushort_t* __restrict__ KH) {
  int m = blockIdx.x * 4 + (threadIdx.x >> 6);
  int d = threadIdx.x & 63;
  const float* src = K + (size_t)m * CD;
#pragma unroll
  for (int h = 0; h < CH; ++h) {
    KH[((size_t)h * M + m) * 64 + d] = f2bf(src[h * CHD + d]);
  }
}

// ---------------- K2 v11: 16 waves, 8 queries/block, il32 packed PV ----------
// Phase 1: wave w (0..15) computes 8-query MFMA scores for strip
// [w*M/16,(w+1)*M/16). Waves 0..7 own query w: full-M mono16 keys in regs,
// barrier-free 16-iter binary search, ballot compaction into il32, w-fill
// packs m | bf16(weight)<<16. PV: wave pair (q,q+8) splits list; ONE
// ds_read_b32 per row gives index+weight; x8-row unroll; pacc combine.
template <int M, int LCAP>
__global__ __launch_bounds__(1024, 1) void attn_v11(
    const float* __restrict__ Q, const ushort_t* __restrict__ KH,
    const float* __restrict__ Vp, const float* __restrict__ imp,
    const float* __restrict__ scal, int scal_idx, int kth,
    float* __restrict__ mem_out, int add_to) {
  constexpr int MP = M + 16;     // padded row (u16)
  constexpr int NGRP = M / 256;  // uint2 per lane covering full M

  __shared__ ushort_t sc_l[8][MP];
  __shared__ unsigned il32[8][LCAP];
  __shared__ float q_l[8][CHD];
  __shared__ float wmax[16][8];
  __shared__ float wsp[8];
  __shared__ int nsel[8];
  __shared__ float4 pacc[8][2][16];

  int tid = threadIdx.x;
  int l = tid & 63;
  int w = tid >> 6;  // 0..15
  int idx = blockIdx.x;
  int sg = idx & (CS / 8 - 1);
  int h = (idx >> 6) & (CH - 1);
  int b = idx >> 10;
  int s0 = sg * 8;
  int h6 = h * CHD;

  if (tid < 512)
    q_l[tid >> 6][tid & 63] = Q[((size_t)(b * CS + s0 + (tid >> 6))) * CD + h6 + (tid & 63)];
  __syncthreads();

  // ---- B-fragments: col = lane&15 (8 real query slots), k = (lane>>4)*8 + j
  int col = l & 15;
  int kbase = (l >> 4) * 8;
  bf16x8 bq0, bq1;
#pragma unroll
  for (int j = 0; j < 8; ++j) { bq0[j] = 0; bq1[j] = 0; }
  if (col < 8) {
#pragma unroll
    for (int j = 0; j < 8; ++j) {
      bq0[j] = (short)f2bf(q_l[col][kbase + j]);
      bq1[j] = (short)f2bf(q_l[col][32 + kbase + j]);
    }
  }

  // ---- phase 1: MFMA scores over strip [w*M/16,(w+1)*M/16), 16-key tiles ----
  float lmax_q = -1e30f;
  const ushort_t* KHh = KH + (size_t)h * M * 64;
#pragma unroll 1
  for (int tile = 0; tile < M / 256; ++tile) {
    int m0 = w * (M / 16) + tile * 16;
    const ushort_t* ka = KHh + (size_t)(m0 + col) * 64 + kbase;
    bf16x8 a0 = *(const bf16x8*)ka;
    bf16x8 a1 = *(const bf16x8*)(ka + 32);
    f32x4 dfrag = {0.f, 0.f, 0.f, 0.f};
    dfrag = __builtin_amdgcn_mfma_f32_16x16x32_bf16(a0, bq0, dfrag, 0, 0, 0);
    dfrag = __builtin_amdgcn_mfma_f32_16x16x32_bf16(a1, bq1, dfrag, 0, 0, 0);
    if (col < 8) {
      int mb = m0 + (l >> 4) * 4;
      float4 ip = *(const float4*)&imp[mb];
      float s0v = dfrag[0] * 0.125f * ip.x;
      float s1v = dfrag[1] * 0.125f * ip.y;
      float s2v = dfrag[2] * 0.125f * ip.z;
      float s3v = dfrag[3] * 0.125f * ip.w;
      lmax_q = fmaxf(lmax_q, fmaxf(fmaxf(s0v, s1v), fmaxf(s2v, s3v)));
      unsigned p0 = (unsigned)f2bf(s0v) | ((unsigned)f2bf(s1v) << 16);
      unsigned p1 = (unsigned)f2bf(s2v) | ((unsigned)f2bf(s3v) << 16);
      *(uint2*)&sc_l[col][mb] = make_uint2(p0, p1);
    }
  }
  lmax_q = fmaxf(lmax_q, __shfl_xor(lmax_q, 16, 64));
  lmax_q = fmaxf(lmax_q, __shfl_xor(lmax_q, 32, 64));
  if (l < 8) wmax[w][l] = lmax_q;
  __syncthreads();

  // ---- select: waves 0..7, wave w owns query w; all in registers ----
  if (w < 8) {
    float t = wmax[0][w];
#pragma unroll
    for (int ww = 1; ww < 16; ++ww) t = fmaxf(t, wmax[ww][w]);

    unsigned mreg[2 * NGRP];
#pragma unroll
    for (int g = 0; g < NGRP; ++g) {
      uint2 sv = *(const uint2*)&sc_l[w][g * 256 + 4 * l];
      mreg[2 * g] = mono16((ushort_t)(sv.x & 0xFFFF)) |
                    (mono16((ushort_t)(sv.x >> 16)) << 16);
      mreg[2 * g + 1] = mono16((ushort_t)(sv.y & 0xFFFF)) |
                        (mono16((ushort_t)(sv.y >> 16)) << 16);
    }

    unsigned lo = 0u, hi = 0xFFFFu;
#pragma unroll 1
    for (int it = 0; it < 16; ++it) {
      unsigned mid = lo + ((hi - lo + 1u) >> 1);
      int cnt = 0;
#pragma unroll
      for (int j = 0; j < 2 * NGRP; ++j) {
        cnt += (int)((mreg[j] & 0xFFFFu) >= mid);
        cnt += (int)((mreg[j] >> 16) >= mid);
      }
#pragma unroll
      for (int off = 1; off < 64; off <<= 1) cnt += __shfl_xor(cnt, off, 64);
      if (cnt >= kth) lo = mid;
      else hi = mid - 1u;
    }
    unsigned thr = lo;

    // ballot compaction (index only for now)
    unsigned long long lt_mask = (1ull << l) - 1ull;
    int pos = 0;
#pragma unroll
    for (int g = 0; g < NGRP; ++g) {
#pragma unroll
      for (int e = 0; e < 4; ++e) {
        unsigned mv = (mreg[2 * g + (e >> 1)] >> ((e & 1) * 16)) & 0xFFFFu;
        bool sel = mv >= thr;
        unsigned long long mask = __ballot(sel);
        if (sel) {
          int p = pos + __builtin_popcountll(mask & lt_mask);
          if (p < LCAP) il32[w][p] = (unsigned)(g * 256 + 4 * l + e);
        }
        pos += __builtin_popcountll(mask);
      }
    }
    int n = pos < LCAP ? pos : LCAP;

    // w-fill: exp once per selected row; pack weight into il32 high16
    float wsum = 0.f;
    for (int i = l; i < n; i += 64) {
      unsigned m = il32[w][i];
      float wv = __expf(bf2f(sc_l[w][m]) - t);
      wsum += wv;
      il32[w][i] = m | ((unsigned)f2bf(wv) << 16);
    }
#pragma unroll
    for (int off = 1; off < 64; off <<= 1) wsum += __shfl_xor(wsum, off, 64);
    if (l == 0) { wsp[w] = wsum; nsel[w] = n; }
  }
  __syncthreads();

  // ---- PV: wave pair (q = w&7, half = w>>3) splits the selected list ----
  {
    int q = w & 7;
    int half = w >> 3;
    int n = nsel[q];
    int n0 = (n >> 1) & ~7;
    int i0 = half ? n0 : 0;
    int i1 = half ? n : n0;
    int g = l >> 4;
    int dl = l & 15;
    const float* Vb = Vp + h6 + 4 * dl;
    f32x4 acc = {0.f, 0.f, 0.f, 0.f};
    int i = i0;
    for (; i + 8 <= i1; i += 8) {  // 8 rows per wave-iter, 2 per lane-group
      unsigned eA = il32[q][i + g];
      unsigned eB = il32[q][i + 4 + g];
      unsigned mA = eA & 0xFFFFu, mB = eB & 0xFFFFu;
      float wA = bf2f((ushort_t)(eA >> 16));
      float wB = bf2f((ushort_t)(eB >> 16));
      float4 vA = *(const float4*)(Vb + ((size_t)mA << 10));
      float4 vB = *(const float4*)(Vb + ((size_t)mB << 10));
      acc[0] += wA * vA.x + wB * vB.x;
      acc[1] += wA * vA.y + wB * vB.y;
      acc[2] += wA * vA.z + wB * vB.z;
      acc[3] += wA * vA.w + wB * vB.w;
    }
    for (; i + 4 <= i1; i += 4) {
      unsigned e = il32[q][i + g];
      unsigned m = e & 0xFFFFu;
      float wv = bf2f((ushort_t)(e >> 16));
      float4 v = *(const float4*)(Vb + ((size_t)m << 10));
      acc[0] += wv * v.x;
      acc[1] += wv * v.y;
      acc[2] += wv * v.z;
      acc[3] += wv * v.w;
    }
    for (; i < i1; ++i) {
      if (g == 0) {
        unsigned e = il32[q][i];
        unsigned m = e & 0xFFFFu;
        float wv = bf2f((ushort_t)(e >> 16));
        float4 v = *(const float4*)(Vb + ((size_t)m << 10));
        acc[0] += wv * v.x;
        acc[1] += wv * v.y;
        acc[2] += wv * v.z;
        acc[3] += wv * v.w;
      }
    }
#pragma unroll
    for (int c = 0; c < 4; ++c) {
      acc[c] += __shfl_xor(acc[c], 16, 64);
      acc[c] += __shfl_xor(acc[c], 32, 64);
    }
    if (l < 16) {
      float4 o;
      o.x = acc[0]; o.y = acc[1]; o.z = acc[2]; o.w = acc[3];
      pacc[q][half][dl] = o;
    }
  }
  __syncthreads();

  if (w < 8 && l < 16) {
    int dl = l;
    float4 p0 = pacc[w][0][dl];
    float4 p1 = pacc[w][1][dl];
    float wsc = scal[scal_idx] / wsp[w];
    size_t off = ((size_t)(b * CS + s0 + w)) * CD + h6 + 4 * dl;
    float4 o;
    o.x = (p0.x + p1.x) * wsc;
    o.y = (p0.y + p1.y) * wsc;
    o.z = (p0.z + p1.z) * wsc;
    o.w = (p0.w + p1.w) * wsc;
    if (add_to) {
      float4 prev = *(const float4*)&mem_out[off];
      o.x += prev.x; o.y += prev.y; o.z += prev.z; o.w += prev.w;
    }
    *(float4*)&mem_out[off] = o;
  }
}

// ---------------- K3: gate + residual + LayerNorm ----------------
__global__ __launch_bounds__(256) void gate_ln_kernel(
    const float* __restrict__ X, const float* __restrict__ Mem,
    const float* __restrict__ Wg, const float* __restrict__ bg,
    const float* __restrict__ lng, const float* __restrict__ lnb,
    float* __restrict__ Out) {
  __shared__ float scr[4];
  int tid = threadIdx.x;
  int row = blockIdx.x;
  int d0 = tid * 4;

  float4 px = *(const float4*)(X + (size_t)row * CD + d0);
  float4 pm = *(const float4*)(Mem + (size_t)row * CD + d0);
  float4 wi = *(const float4*)(Wg + d0);
  float4 wm = *(const float4*)(Wg + CD + d0);

  float t = px.x * wi.x + px.y * wi.y + px.z * wi.z + px.w * wi.w +
            pm.x * wm.x + pm.y * wm.y + pm.z * wm.z + pm.w * wm.w;
  float z = block_sum_f(t, scr, tid) + bg[0];
  float gate = 1.f / (1.f + __expf(-z));

  float xr0 = px.x + pm.x * gate;
  float xr1 = px.y + pm.y * gate;
  float xr2 = px.z + pm.z * gate;
  float xr3 = px.w + pm.w * gate;

  float ssum = block_sum_f(xr0 + xr1 + xr2 + xr3, scr, tid);
  float ssq = block_sum_f(xr0 * xr0 + xr1 * xr1 + xr2 * xr2 + xr3 * xr3, scr, tid);
  float mu = ssum * (1.f / CD);
  float var = ssq * (1.f / CD) - mu * mu;
  float inv = rsqrtf(var + 1e-5f);

  float4 pg = *(const float4*)(lng + d0);
  float4 pb = *(const float4*)(lnb + d0);
  float4 o;
  o.x = (xr0 - mu) * inv * pg.x + pb.x;
  o.y = (xr1 - mu) * inv * pg.y + pb.y;
  o.z = (xr2 - mu) * inv * pg.z + pb.z;
  o.w = (xr3 - mu) * inv * pg.w + pb.w;
  *(float4*)(Out + (size_t)row * CD + d0) = o;
}

extern "C" void kernel_launch(void* const* d_in, const int* in_sizes, int n_in,
                              void* d_out, int out_size, void* d_ws, size_t ws_size,
                              hipStream_t stream) {
  const float* inputs = (const float*)d_in[0];
  const float* Wq = (const float*)d_in[1];
  const float* bq = (const float*)d_in[2];
  const float* st_keys = (const float*)d_in[3];
  const float* st_values = (const float*)d_in[4];
  const float* lt_keys = (const float*)d_in[5];
  const float* lt_values = (const float*)d_in[6];
  const float* st_imp = (const float*)d_in[7];
  const float* lt_imp = (const float*)d_in[8];
  const float* Wg = (const float*)d_in[9];
  const float* bg = (const float*)d_in[10];
  const float* ln_g = (const float*)d_in[11];
  const float* ln_b = (const float*)d_in[12];
  float* out = (float*)d_out;

  size_t nQ = (size_t)CB * CS * CD;
  float* Qws = (float*)d_ws;
  float* Memws = Qws + nQ;
  float* scal = Memws + nQ;
  ushort_t* KHst = (ushort_t*)(scal + 64);
  ushort_t* KHlt = KHst + (size_t)CD * CST;

  int nblk8 = CB * CH * (CS / 8);  // 2048

  prep_kernel<<<1, 256, 0, stream>>>(st_imp, lt_imp, scal);
  qproj_mfma<<<256, 256, 0, stream>>>(inputs, Wq, bq, Qws);
  krepack_kernel<CST><<<CST / 4, 256, 0, stream>>>(st_keys, KHst);
  krepack_kernel<CLT><<<CLT / 4, 256, 0, stream>>>(lt_keys, KHlt);
  attn_v11<CST, 320><<<nblk8, 1024, 0, stream>>>(
      Qws, KHst, st_values, st_imp, scal, 0, CKST, Memws, 0);
  attn_v11<CLT, 896><<<nblk8, 1024, 0, stream>>>(
      Qws, KHlt, lt_values, lt_imp, scal, 1, CKLT, Memws, 1);
  gate_ln_kernel<<<CB * CS, 256, 0, stream>>>(inputs, Memws, Wg, bg, ln_g, ln_b, out);
}

// Round 17
// 739.724 us; speedup vs baseline: 1.3519x; 1.0710x over previous
//
#include <hip/hip_runtime.h>
#include <hip/hip_bf16.h>

typedef unsigned short ushort_t;
typedef __attribute__((ext_vector_type(8))) short bf16x8;
typedef __attribute__((ext_vector_type(4))) float f32x4;

constexpr int CB = 2, CS = 512, CD = 1024, CH = 16, CHD = 64;
constexpr int CST = 2048, CLT = 6144;
constexpr int CKST = 204, CKLT = 614;

__device__ __forceinline__ float u2f(unsigned u) { return __uint_as_float(u); }
__device__ __forceinline__ float bf2f(ushort_t u) {
  return __uint_as_float(((unsigned)u) << 16);
}
__device__ __forceinline__ ushort_t f2bf(float f) {
  __hip_bfloat16 h = __float2bfloat16(f);
  return *reinterpret_cast<ushort_t*>(&h);
}
// monotone 16-bit key: mono(a) > mono(b) <=> bf16 a > b
__device__ __forceinline__ unsigned mono16(ushort_t u) {
  return (u & 0x8000) ? (unsigned)((ushort_t)~u) : (unsigned)(u | 0x8000);
}

__device__ __forceinline__ float block_sum_f(float v, float* scratch, int tid) {
#pragma unroll
  for (int o = 32; o > 0; o >>= 1) v += __shfl_down(v, o, 64);
  if ((tid & 63) == 0) scratch[tid >> 6] = v;
  __syncthreads();
  float r = (scratch[0] + scratch[1]) + (scratch[2] + scratch[3]);
  __syncthreads();
  return r;
}

// ---------------- K0: bank-mix coefficients ----------------
__global__ __launch_bounds__(256) void prep_kernel(
    const float* __restrict__ st_imp, const float* __restrict__ lt_imp,
    float* __restrict__ scal) {
  __shared__ float scr[4];
  int tid = threadIdx.x;
  float s = 0.f, l = 0.f;
  for (int i = tid; i < CST; i += 256) s += st_imp[i];
  for (int i = tid; i < CLT; i += 256) l += lt_imp[i];
  float ssum = block_sum_f(s, scr, tid);
  float lsum = block_sum_f(l, scr, tid);
  if (tid == 0) {
    float sw = 1.f / (1.f + __expf(-(ssum / CST)));
    float lw = 1.f / (1.f + __expf(-(lsum / CLT)));
    float tot = sw + lw;
    scal[0] = sw / tot;
    scal[1] = lw / tot;
  }
}

// ---------------- K1: MFMA qproj: Q = X @ Wq + bq (fp32 out) ------------------
__global__ __launch_bounds__(256) void qproj_mfma(
    const float* __restrict__ X, const float* __restrict__ Wq,
    const float* __restrict__ bq, float* __restrict__ Qout) {
  __shared__ ushort_t As[64][40];   // X tile  [row][k]
  __shared__ ushort_t BsT[64][40];  // Wq tile [col][k] (transposed)
  int tid = threadIdx.x;
  int l = tid & 63;
  int w = tid >> 6;
  int bm = (blockIdx.x >> 4) * 64;
  int bn = (blockIdx.x & 15) * 64;

  int arow = l & 15;
  int koff = (l >> 4) * 8;

  f32x4 acc[4];
#pragma unroll
  for (int c = 0; c < 4; ++c) acc[c] = {0.f, 0.f, 0.f, 0.f};

  for (int k0 = 0; k0 < CD; k0 += 32) {
#pragma unroll
    for (int e = 0; e < 2; ++e) {
      int idx = tid + e * 256;
      int r = idx >> 3;
      int kk4 = (idx & 7) * 4;
      float4 v = *(const float4*)&X[(size_t)(bm + r) * CD + k0 + kk4];
      uint2 p;
      p.x = (unsigned)f2bf(v.x) | ((unsigned)f2bf(v.y) << 16);
      p.y = (unsigned)f2bf(v.z) | ((unsigned)f2bf(v.w) << 16);
      *(uint2*)&As[r][kk4] = p;
    }
#pragma unroll
    for (int e = 0; e < 2; ++e) {
      int idx = tid + e * 256;
      int kk = idx >> 4;
      int nn4 = (idx & 15) * 4;
      float4 v = *(const float4*)&Wq[(size_t)(k0 + kk) * CD + bn + nn4];
      BsT[nn4 + 0][kk] = f2bf(v.x);
      BsT[nn4 + 1][kk] = f2bf(v.y);
      BsT[nn4 + 2][kk] = f2bf(v.z);
      BsT[nn4 + 3][kk] = f2bf(v.w);
    }
    __syncthreads();

    bf16x8 af = *(const bf16x8*)&As[w * 16 + arow][koff];
#pragma unroll
    for (int c = 0; c < 4; ++c) {
      bf16x8 bfv = *(const bf16x8*)&BsT[c * 16 + arow][koff];
      acc[c] = __builtin_amdgcn_mfma_f32_16x16x32_bf16(af, bfv, acc[c], 0, 0, 0);
    }
    __syncthreads();
  }

  int col = l & 15;
  int row4 = (l >> 4) * 4;
#pragma unroll
  for (int c = 0; c < 4; ++c) {
    float bb = bq[bn + c * 16 + col];
#pragma unroll
    for (int r = 0; r < 4; ++r)
      Qout[(size_t)(bm + w * 16 + row4 + r) * CD + bn + c * 16 + col] =
          acc[c][r] + bb;
  }
}

// ---------------- K-repack: K[m][h*64+d] f32 -> KH[h][m][64] bf16 -------------
template <int M>
__global__ __launch_bounds__(256) void krepack_kernel(
    const float* __restrict__ K, ushort_t* __restrict__ KH) {
  int m = blockIdx.x * 4 + (threadIdx.x >> 6);
  int d = threadIdx.x & 63;
  const float* src = K + (size_t)m * CD;
#pragma unroll
  for (int h = 0; h < CH; ++h) {
    KH[((size_t)h * M + m) * 64 + d] = f2bf(src[h * CHD + d]);
  }
}

// ---------------- K2 v13: v11 + half-register pair-split select ---------------
// 16 waves, 8 queries/block. Phase 1: v11's MFMA scores (unchanged).
// Select: wave (wq=w&7, shalf=w>>3) holds only its HALF of query wq's keys
// (mreg[2*HG], half of v11's per-wave registers). 16-iter binary search with
// per-iter double-buffered LDS count exchange (uniform barriers, v6 pattern).
// Half-count exchange -> disjoint ballot compaction -> split w-fill.
// PV: v11's il32 single-read pair-split (unchanged). MP=M+4 bank padding.
template <int M, int LCAP>
__global__ __launch_bounds__(1024, 1) void attn_v13(
    const float* __restrict__ Q, const ushort_t* __restrict__ KH,
    const float* __restrict__ Vp, const float* __restrict__ imp,
    const float* __restrict__ scal, int scal_idx, int kth,
    float* __restrict__ mem_out, int add_to) {
  constexpr int MP = M + 4;      // padded row (u16): row-to-row bank shift 2
  constexpr int NGRP = M / 256;  // uint2-groups covering full M
  constexpr int HG = NGRP / 2;   // groups per half

  __shared__ ushort_t sc_l[8][MP];
  __shared__ unsigned il32[8][LCAP];
  __shared__ float q_l[8][CHD];
  __shared__ float wmax[16][8];
  __shared__ int cntw[2][8][2];
  __shared__ int hcnt[8][2];
  __shared__ float wsp2[8][2];
  __shared__ int nsel[8];
  __shared__ float4 pacc[8][2][16];

  int tid = threadIdx.x;
  int l = tid & 63;
  int w = tid >> 6;  // 0..15
  int idx = blockIdx.x;
  int sg = idx & (CS / 8 - 1);
  int h = (idx >> 6) & (CH - 1);
  int b = idx >> 10;
  int s0 = sg * 8;
  int h6 = h * CHD;

  if (tid < 512)
    q_l[tid >> 6][tid & 63] = Q[((size_t)(b * CS + s0 + (tid >> 6))) * CD + h6 + (tid & 63)];
  __syncthreads();

  // ---- B-fragments: col = lane&15 (8 real query slots), k = (lane>>4)*8 + j
  int col = l & 15;
  int kbase = (l >> 4) * 8;
  bf16x8 bq0, bq1;
#pragma unroll
  for (int j = 0; j < 8; ++j) { bq0[j] = 0; bq1[j] = 0; }
  if (col < 8) {
#pragma unroll
    for (int j = 0; j < 8; ++j) {
      bq0[j] = (short)f2bf(q_l[col][kbase + j]);
      bq1[j] = (short)f2bf(q_l[col][32 + kbase + j]);
    }
  }

  // ---- phase 1: MFMA scores over strip [w*M/16,(w+1)*M/16), 16-key tiles ----
  float lmax_q = -1e30f;
  const ushort_t* KHh = KH + (size_t)h * M * 64;
#pragma unroll 1
  for (int tile = 0; tile < M / 256; ++tile) {
    int m0 = w * (M / 16) + tile * 16;
    const ushort_t* ka = KHh + (size_t)(m0 + col) * 64 + kbase;
    bf16x8 a0 = *(const bf16x8*)ka;
    bf16x8 a1 = *(const bf16x8*)(ka + 32);
    f32x4 dfrag = {0.f, 0.f, 0.f, 0.f};
    dfrag = __builtin_amdgcn_mfma_f32_16x16x32_bf16(a0, bq0, dfrag, 0, 0, 0);
    dfrag = __builtin_amdgcn_mfma_f32_16x16x32_bf16(a1, bq1, dfrag, 0, 0, 0);
    if (col < 8) {
      int mb = m0 + (l >> 4) * 4;
      float4 ip = *(const float4*)&imp[mb];
      float s0v = dfrag[0] * 0.125f * ip.x;
      float s1v = dfrag[1] * 0.125f * ip.y;
      float s2v = dfrag[2] * 0.125f * ip.z;
      float s3v = dfrag[3] * 0.125f * ip.w;
      lmax_q = fmaxf(lmax_q, fmaxf(fmaxf(s0v, s1v), fmaxf(s2v, s3v)));
      unsigned p0 = (unsigned)f2bf(s0v) | ((unsigned)f2bf(s1v) << 16);
      unsigned p1 = (unsigned)f2bf(s2v) | ((unsigned)f2bf(s3v) << 16);
      *(uint2*)&sc_l[col][mb] = make_uint2(p0, p1);
    }
  }
  lmax_q = fmaxf(lmax_q, __shfl_xor(lmax_q, 16, 64));
  lmax_q = fmaxf(lmax_q, __shfl_xor(lmax_q, 32, 64));
  if (l < 8) wmax[w][l] = lmax_q;
  __syncthreads();

  // ---- select: wave (wq, shalf) owns half of query wq's keys ----
  int wq = w & 7;
  int shalf = w >> 3;
  float t = wmax[0][wq];
#pragma unroll
  for (int ww = 1; ww < 16; ++ww) t = fmaxf(t, wmax[ww][wq]);

  int mbase = shalf * (M / 2);
  unsigned mreg[2 * HG];
#pragma unroll
  for (int g = 0; g < HG; ++g) {
    uint2 sv = *(const uint2*)&sc_l[wq][mbase + g * 256 + 4 * l];
    mreg[2 * g] = mono16((ushort_t)(sv.x & 0xFFFF)) |
                  (mono16((ushort_t)(sv.x >> 16)) << 16);
    mreg[2 * g + 1] = mono16((ushort_t)(sv.y & 0xFFFF)) |
                      (mono16((ushort_t)(sv.y >> 16)) << 16);
  }

  // 16-iter binary search; per-iter cross-wave count exchange (uniform barriers)
  unsigned lo = 0u, hi = 0xFFFFu;
#pragma unroll 1
  for (int it = 0; it < 16; ++it) {
    unsigned mid = lo + ((hi - lo + 1u) >> 1);
    int cnt = 0;
#pragma unroll
    for (int j = 0; j < 2 * HG; ++j) {
      cnt += (int)((mreg[j] & 0xFFFFu) >= mid);
      cnt += (int)((mreg[j] >> 16) >= mid);
    }
#pragma unroll
    for (int off = 1; off < 64; off <<= 1) cnt += __shfl_xor(cnt, off, 64);
    if (l == 0) cntw[it & 1][wq][shalf] = cnt;
    __syncthreads();
    int tot = cntw[it & 1][wq][0] + cntw[it & 1][wq][1];
    if (tot >= kth) lo = mid;
    else hi = mid - 1u;
  }
  unsigned thr = lo;

  // half-count at thr -> base exchange
  {
    int c = 0;
#pragma unroll
    for (int j = 0; j < 2 * HG; ++j) {
      c += (int)((mreg[j] & 0xFFFFu) >= thr);
      c += (int)((mreg[j] >> 16) >= thr);
    }
#pragma unroll
    for (int off = 1; off < 64; off <<= 1) c += __shfl_xor(c, off, 64);
    if (l == 0) hcnt[wq][shalf] = c;
  }
  __syncthreads();
  int cnt0 = hcnt[wq][0];
  int ntot = cnt0 + hcnt[wq][1];
  int nclamp = ntot < LCAP ? ntot : LCAP;
  int c0 = cnt0 < LCAP ? cnt0 : LCAP;

  // ballot compaction of own half into disjoint il32 range
  unsigned long long lt_mask = (1ull << l) - 1ull;
  int pos = shalf ? cnt0 : 0;
#pragma unroll
  for (int g = 0; g < HG; ++g) {
#pragma unroll
    for (int e = 0; e < 4; ++e) {
      unsigned mv = (mreg[2 * g + (e >> 1)] >> ((e & 1) * 16)) & 0xFFFFu;
      bool sel = mv >= thr;
      unsigned long long mask = __ballot(sel);
      if (sel) {
        int p = pos + __builtin_popcountll(mask & lt_mask);
        if (p < LCAP) il32[wq][p] = (unsigned)(mbase + g * 256 + 4 * l + e);
      }
      pos += __builtin_popcountll(mask);
    }
  }
  if (shalf == 0 && l == 0) nsel[wq] = nclamp;
  __syncthreads();

  // ---- w-fill split: each wave fills its own compacted range ----
  {
    int f0 = shalf ? c0 : 0;
    int f1 = shalf ? nclamp : c0;
    float wsum = 0.f;
    for (int i = f0 + l; i < f1; i += 64) {
      unsigned m = il32[wq][i];
      float wv = __expf(bf2f(sc_l[wq][m]) - t);
      wsum += wv;
      il32[wq][i] = m | ((unsigned)f2bf(wv) << 16);
    }
#pragma unroll
    for (int off = 1; off < 64; off <<= 1) wsum += __shfl_xor(wsum, off, 64);
    if (l == 0) wsp2[wq][shalf] = wsum;
  }
  __syncthreads();

  // ---- PV: wave pair (wq, shalf) splits the selected list ----
  {
    int n = nsel[wq];
    int n0 = (n >> 1) & ~7;
    int i0 = shalf ? n0 : 0;
    int i1 = shalf ? n : n0;
    int g = l >> 4;
    int dl = l & 15;
    const float* Vb = Vp + h6 + 4 * dl;
    f32x4 acc = {0.f, 0.f, 0.f, 0.f};
    int i = i0;
    for (; i + 8 <= i1; i += 8) {
      unsigned eA = il32[wq][i + g];
      unsigned eB = il32[wq][i + 4 + g];
      unsigned mA = eA & 0xFFFFu, mB = eB & 0xFFFFu;
      float wA = bf2f((ushort_t)(eA >> 16));
      float wB = bf2f((ushort_t)(eB >> 16));
      float4 vA = *(const float4*)(Vb + ((size_t)mA << 10));
      float4 vB = *(const float4*)(Vb + ((size_t)mB << 10));
      acc[0] += wA * vA.x + wB * vB.x;
      acc[1] += wA * vA.y + wB * vB.y;
      acc[2] += wA * vA.z + wB * vB.z;
      acc[3] += wA * vA.w + wB * vB.w;
    }
    for (; i + 4 <= i1; i += 4) {
      unsigned e = il32[wq][i + g];
      unsigned m = e & 0xFFFFu;
      float wv = bf2f((ushort_t)(e >> 16));
      float4 v = *(const float4*)(Vb + ((size_t)m << 10));
      acc[0] += wv * v.x;
      acc[1] += wv * v.y;
      acc[2] += wv * v.z;
      acc[3] += wv * v.w;
    }
    for (; i < i1; ++i) {
      if (g == 0) {
        unsigned e = il32[wq][i];
        unsigned m = e & 0xFFFFu;
        float wv = bf2f((ushort_t)(e >> 16));
        float4 v = *(const float4*)(Vb + ((size_t)m << 10));
        acc[0] += wv * v.x;
        acc[1] += wv * v.y;
        acc[2] += wv * v.z;
        acc[3] += wv * v.w;
      }
    }
#pragma unroll
    for (int c = 0; c < 4; ++c) {
      acc[c] += __shfl_xor(acc[c], 16, 64);
      acc[c] += __shfl_xor(acc[c], 32, 64);
    }
    if (l < 16) {
      float4 o;
      o.x = acc[0]; o.y = acc[1]; o.z = acc[2]; o.w = acc[3];
      pacc[wq][shalf][l & 15] = o;
    }
  }
  __syncthreads();

  if (w < 8 && l < 16) {
    int dl = l;
    float4 p0 = pacc[w][0][dl];
    float4 p1 = pacc[w][1][dl];
    float wsc = scal[scal_idx] / (wsp2[w][0] + wsp2[w][1]);
    size_t off = ((size_t)(b * CS + s0 + w)) * CD + h6 + 4 * dl;
    float4 o;
    o.x = (p0.x + p1.x) * wsc;
    o.y = (p0.y + p1.y) * wsc;
    o.z = (p0.z + p1.z) * wsc;
    o.w = (p0.w + p1.w) * wsc;
    if (add_to) {
      float4 prev = *(const float4*)&mem_out[off];
      o.x += prev.x; o.y += prev.y; o.z += prev.z; o.w += prev.w;
    }
    *(float4*)&mem_out[off] = o;
  }
}

// ---------------- K3: gate + residual + LayerNorm ----------------
__global__ __launch_bounds__(256) void gate_ln_kernel(
    const float* __restrict__ X, const float* __restrict__ Mem,
    const float* __restrict__ Wg, const float* __restrict__ bg,
    const float* __restrict__ lng, const float* __restrict__ lnb,
    float* __restrict__ Out) {
  __shared__ float scr[4];
  int tid = threadIdx.x;
  int row = blockIdx.x;
  int d0 = tid * 4;

  float4 px = *(const float4*)(X + (size_t)row * CD + d0);
  float4 pm = *(const float4*)(Mem + (size_t)row * CD + d0);
  float4 wi = *(const float4*)(Wg + d0);
  float4 wm = *(const float4*)(Wg + CD + d0);

  float t = px.x * wi.x + px.y * wi.y + px.z * wi.z + px.w * wi.w +
            pm.x * wm.x + pm.y * wm.y + pm.z * wm.z + pm.w * wm.w;
  float z = block_sum_f(t, scr, tid) + bg[0];
  float gate = 1.f / (1.f + __expf(-z));

  float xr0 = px.x + pm.x * gate;
  float xr1 = px.y + pm.y * gate;
  float xr2 = px.z + pm.z * gate;
  float xr3 = px.w + pm.w * gate;

  float ssum = block_sum_f(xr0 + xr1 + xr2 + xr3, scr, tid);
  float ssq = block_sum_f(xr0 * xr0 + xr1 * xr1 + xr2 * xr2 + xr3 * xr3, scr, tid);
  float mu = ssum * (1.f / CD);
  float var = ssq * (1.f / CD) - mu * mu;
  float inv = rsqrtf(var + 1e-5f);

  float4 pg = *(const float4*)(lng + d0);
  float4 pb = *(const float4*)(lnb + d0);
  float4 o;
  o.x = (xr0 - mu) * inv * pg.x + pb.x;
  o.y = (xr1 - mu) * inv * pg.y + pb.y;
  o.z = (xr2 - mu) * inv * pg.z + pb.z;
  o.w = (xr3 - mu) * inv * pg.w + pb.w;
  *(float4*)(Out + (size_t)row * CD + d0) = o;
}

extern "C" void kernel_launch(void* const* d_in, const int* in_sizes, int n_in,
                              void* d_out, int out_size, void* d_ws, size_t ws_size,
                              hipStream_t stream) {
  const float* inputs = (const float*)d_in[0];
  const float* Wq = (const float*)d_in[1];
  const float* bq = (const float*)d_in[2];
  const float* st_keys = (const float*)d_in[3];
  const float* st_values = (const float*)d_in[4];
  const float* lt_keys = (const float*)d_in[5];
  const float* lt_values = (const float*)d_in[6];
  const float* st_imp = (const float*)d_in[7];
  const float* lt_imp = (const float*)d_in[8];
  const float* Wg = (const float*)d_in[9];
  const float* bg = (const float*)d_in[10];
  const float* ln_g = (const float*)d_in[11];
  const float* ln_b = (const float*)d_in[12];
  float* out = (float*)d_out;

  size_t nQ = (size_t)CB * CS * CD;
  float* Qws = (float*)d_ws;
  float* Memws = Qws + nQ;
  float* scal = Memws + nQ;
  ushort_t* KHst = (ushort_t*)(scal + 64);
  ushort_t* KHlt = KHst + (size_t)CD * CST;

  int nblk8 = CB * CH * (CS / 8);  // 2048

  prep_kernel<<<1, 256, 0, stream>>>(st_imp, lt_imp, scal);
  qproj_mfma<<<256, 256, 0, stream>>>(inputs, Wq, bq, Qws);
  krepack_kernel<CST><<<CST / 4, 256, 0, stream>>>(st_keys, KHst);
  krepack_kernel<CLT><<<CLT / 4, 256, 0, stream>>>(lt_keys, KHlt);
  attn_v13<CST, 320><<<nblk8, 1024, 0, stream>>>(
      Qws, KHst, st_values, st_imp, scal, 0, CKST, Memws, 0);
  attn_v13<CLT, 896><<<nblk8, 1024, 0, stream>>>(
      Qws, KHlt, lt_values, lt_imp, scal, 1, CKLT, Memws, 1);
  gate_ln_kernel<<<CB * CS, 256, 0, stream>>>(inputs, Memws, Wg, bg, ln_g, ln_b, out);
}